// Round 1
// baseline (5559.179 us; speedup 1.0000x reference)
//
#include <hip/hip_runtime.h>
#include <math.h>

// Round 1: correctness-first, fp32 everywhere.
// Rationale: MoE routing (top-2 + capacity cutoff) is discontinuous; bf16 in the
// attention path would flip routing on near-ties and blow past absmax 0.1.
// Layout constants (fixed by problem):
//   B=2 T=2048 D=1024 NH=16 HD=64 HALF=32 NEXP=8 TOPK=2 CAP=1024 FF=4096

#define TT 2048
#define NTOK 4096   // B*T

// ---------------------------------------------------------------- LayerNorm
__global__ __launch_bounds__(256)
void ln_kernel(const float* __restrict__ x, const float* __restrict__ g,
               const float* __restrict__ b, float* __restrict__ out) {
  int row = blockIdx.x, tid = threadIdx.x;
  const float4* xr = (const float4*)(x + (size_t)row * 1024);
  float4 v = xr[tid];                       // 256 threads * 4 = 1024
  float s = v.x + v.y + v.z + v.w;
  #pragma unroll
  for (int off = 1; off < 64; off <<= 1) s += __shfl_xor(s, off);
  __shared__ float red1[4], red2[4];
  if ((tid & 63) == 0) red1[tid >> 6] = s;
  __syncthreads();
  float mu = (red1[0] + red1[1] + red1[2] + red1[3]) * (1.0f / 1024.0f);
  float dx = v.x - mu, dy = v.y - mu, dz = v.z - mu, dw = v.w - mu;
  float ss = dx*dx + dy*dy + dz*dz + dw*dw;
  #pragma unroll
  for (int off = 1; off < 64; off <<= 1) ss += __shfl_xor(ss, off);
  if ((tid & 63) == 0) red2[tid >> 6] = ss;
  __syncthreads();
  float var = (red2[0] + red2[1] + red2[2] + red2[3]) * (1.0f / 1024.0f);
  float inv = 1.0f / sqrtf(var + 1e-5f);
  float4 g4 = ((const float4*)g)[tid];
  float4 b4 = ((const float4*)b)[tid];
  float4 o4;
  o4.x = dx * inv * g4.x + b4.x;
  o4.y = dy * inv * g4.y + b4.y;
  o4.z = dz * inv * g4.z + b4.z;
  o4.w = dw * inv * g4.w + b4.w;
  ((float4*)(out + (size_t)row * 1024))[tid] = o4;   // safe in-place (own elems only)
}

// ---------------------------------------------------------------- RoPE table (f64 to match np ref)
__global__ void sincos_kernel(float* __restrict__ st, float* __restrict__ ct) {
  int t = blockIdx.x, j = threadIdx.x;      // 2048 x 32
  double invf = pow(10000.0, -((double)(2 * j)) / 64.0);
  double ang = (double)t * invf;
  st[t * 32 + j] = (float)sin(ang);
  ct[t * 32 + j] = (float)cos(ang);
}

// ---------------------------------------------------------------- RoPE apply + emit k,v outputs
__global__ __launch_bounds__(256)
void rope_kernel(float* __restrict__ qkv, const float* __restrict__ st,
                 const float* __restrict__ ct, float* __restrict__ kout,
                 float* __restrict__ vout) {
  int row = blockIdx.x;                     // b*T + t
  int t = row & (TT - 1);
  int tid = threadIdx.x;
  float* base = qkv + (size_t)row * 3072;
  #pragma unroll
  for (int l = 0; l < 2; ++l) {
    int idx = l * 256 + tid;                // 0..511 -> h (16) x j (32)
    int h = idx >> 5, j = idx & 31;
    float s = st[t * 32 + j], c = ct[t * 32 + j];
    float* qp = base + h * 192;
    float q1 = qp[j], q2 = qp[j + 32];
    qp[j]      = q1 * c - q2 * s;
    qp[j + 32] = q1 * s + q2 * c;
    float k1 = qp[64 + j], k2 = qp[96 + j];
    float kr1 = k1 * c - k2 * s, kr2 = k1 * s + k2 * c;
    qp[64 + j] = kr1; qp[96 + j] = kr2;
    kout[(size_t)row * 1024 + h * 64 + j]      = kr1;
    kout[(size_t)row * 1024 + h * 64 + 32 + j] = kr2;
  }
  #pragma unroll
  for (int l = 0; l < 4; ++l) {
    int f = l * 256 + tid;                  // 0..1023
    int h = f >> 6, d = f & 63;
    vout[(size_t)row * 1024 + f] = base[h * 192 + 128 + d];
  }
}

// ---------------------------------------------------------------- causal flash attention (fp32)
// one block per (q-tile of 64, head, batch); 256 thr; thread = (i4,j4) 4x4 micro-tile
__global__ __launch_bounds__(256)
void flash_kernel(const float* __restrict__ qkv, float* __restrict__ o) {
  __shared__ __align__(16) float Qs[64][68];
  __shared__ __align__(16) float Ks[64][68];
  __shared__ __align__(16) float Vs[64][68];
  int qt = blockIdx.x, h = blockIdx.y, b = blockIdx.z;
  int tid = threadIdx.x, lane = tid & 63;
  int i4 = tid >> 4, j4 = tid & 15;
  int iR = i4 * 4, jC = j4 * 4;
  size_t bT = (size_t)b * TT;
  int q0 = qt * 64;
  // load Q tile once
  #pragma unroll
  for (int l = 0; l < 4; ++l) {
    int idx = l * 256 + tid;
    int r = idx >> 4, c4 = (idx & 15) * 4;
    *(float4*)&Qs[r][c4] = *(const float4*)&qkv[(bT + q0 + r) * 3072 + h * 192 + c4];
  }
  float accO[4][4] = {};
  float mrow[4] = {-3.402823466e38f, -3.402823466e38f, -3.402823466e38f, -3.402823466e38f};
  float lrow[4] = {};
  for (int kt = 0; kt <= qt; ++kt) {
    __syncthreads();                        // prev PV done; Q stores visible (kt==0)
    #pragma unroll
    for (int l = 0; l < 4; ++l) {
      int idx = l * 256 + tid;
      int r = idx >> 4, c4 = (idx & 15) * 4;
      size_t gb = (bT + kt * 64 + r) * 3072 + h * 192;
      *(float4*)&Ks[r][c4] = *(const float4*)&qkv[gb + 64 + c4];
      *(float4*)&Vs[r][c4] = *(const float4*)&qkv[gb + 128 + c4];
    }
    __syncthreads();
    float s[4][4] = {};
    #pragma unroll
    for (int d4 = 0; d4 < 16; ++d4) {
      float4 qv[4], kv[4];
      #pragma unroll
      for (int r = 0; r < 4; ++r) qv[r] = *(const float4*)&Qs[iR + r][d4 * 4];
      #pragma unroll
      for (int c = 0; c < 4; ++c) kv[c] = *(const float4*)&Ks[jC + c][d4 * 4];
      #pragma unroll
      for (int r = 0; r < 4; ++r)
        #pragma unroll
        for (int c = 0; c < 4; ++c)
          s[r][c] += qv[r].x * kv[c].x + qv[r].y * kv[c].y + qv[r].z * kv[c].z + qv[r].w * kv[c].w;
    }
    // scale + causal mask (matches ref: att*scale then where(causal, ., finfo.min))
    #pragma unroll
    for (int r = 0; r < 4; ++r)
      #pragma unroll
      for (int c = 0; c < 4; ++c) {
        float sv = s[r][c] * 0.125f;
        if (kt * 64 + jC + c > q0 + iR + r) sv = -3.402823466e38f;
        s[r][c] = sv;
      }
    // online softmax per row (16-lane row group)
    #pragma unroll
    for (int r = 0; r < 4; ++r) {
      float rm = fmaxf(fmaxf(s[r][0], s[r][1]), fmaxf(s[r][2], s[r][3]));
      #pragma unroll
      for (int off = 1; off < 16; off <<= 1) rm = fmaxf(rm, __shfl_xor(rm, off));
      float mnew = fmaxf(mrow[r], rm);
      float f = expf(mrow[r] - mnew);
      float psum = 0.0f;
      #pragma unroll
      for (int c = 0; c < 4; ++c) { float p = expf(s[r][c] - mnew); s[r][c] = p; psum += p; }
      #pragma unroll
      for (int off = 1; off < 16; off <<= 1) psum += __shfl_xor(psum, off);
      lrow[r] = lrow[r] * f + psum;
      mrow[r] = mnew;
      #pragma unroll
      for (int c = 0; c < 4; ++c) accO[r][c] *= f;
    }
    // PV via in-wave shuffle of P (no Ps LDS buffer)
    #pragma unroll
    for (int j = 0; j < 64; ++j) {
      float4 vv = *(const float4*)&Vs[j][jC];
      int srcLane = (lane & 48) | (j >> 2);
      float p0 = __shfl(s[0][j & 3], srcLane);
      float p1 = __shfl(s[1][j & 3], srcLane);
      float p2 = __shfl(s[2][j & 3], srcLane);
      float p3 = __shfl(s[3][j & 3], srcLane);
      accO[0][0] += p0 * vv.x; accO[0][1] += p0 * vv.y; accO[0][2] += p0 * vv.z; accO[0][3] += p0 * vv.w;
      accO[1][0] += p1 * vv.x; accO[1][1] += p1 * vv.y; accO[1][2] += p1 * vv.z; accO[1][3] += p1 * vv.w;
      accO[2][0] += p2 * vv.x; accO[2][1] += p2 * vv.y; accO[2][2] += p2 * vv.z; accO[2][3] += p2 * vv.w;
      accO[3][0] += p3 * vv.x; accO[3][1] += p3 * vv.y; accO[3][2] += p3 * vv.z; accO[3][3] += p3 * vv.w;
    }
  }
  #pragma unroll
  for (int r = 0; r < 4; ++r) {
    float inv = 1.0f / lrow[r];
    float4 o4 = { accO[r][0] * inv, accO[r][1] * inv, accO[r][2] * inv, accO[r][3] * inv };
    *(float4*)&o[(bT + q0 + iR + r) * 1024 + h * 64 + jC] = o4;
  }
}

// ---------------------------------------------------------------- SGEMM (fp32, 128x128x8, 8x8/thread)
// MODE 0: C = A@B                         (QKV)
// MODE 1: C = A@B + extra (elementwise)   (proj + residual)
// MODE 2: h = gelu(gather(A)@W1[e] + b1)  (expert up)
// MODE 3: out[tok] += (A@W2[e] + b2)*w    (expert down, split-K, atomic)
template <int MODE>
__global__ __launch_bounds__(256)
void sgemm_kernel(const float* __restrict__ Ag, const float* __restrict__ Bg,
                  float* __restrict__ Cg, const float* __restrict__ extra,
                  const int* __restrict__ etok, const float* __restrict__ ew,
                  const int* __restrict__ ecnt,
                  int M, int N, int K, int eBase, int ksplit, long hstride) {
  int e = 0, kc = 0;
  const float* Ap = Ag; const float* Bp = Bg; float* Cp = Cg;
  const float* bias = nullptr; const int* gat = nullptr; const float* wv = nullptr;
  if (MODE == 2) {
    int z = blockIdx.z; e = eBase + z;
    Bp = Bg + (size_t)e * K * N;
    bias = extra + (size_t)e * N;
    gat = etok + e * 1024;
    Cp = Cg + (size_t)z * hstride;
  }
  if (MODE == 3) {
    int z = blockIdx.z; e = eBase + z / ksplit; kc = z % ksplit;
    Ap = Ag + (size_t)(z / ksplit) * hstride;
    Bp = Bg + (size_t)e * K * N;
    bias = extra + (size_t)e * N;
    gat = etok + e * 1024; wv = ew + e * 1024;
  }
  int k_begin = 0, k_end = K;
  if (MODE == 3) { int kch = K / ksplit; k_begin = kc * kch; k_end = k_begin + kch; }

  int bm = blockIdx.y * 128, bn = blockIdx.x * 128;
  int tid = threadIdx.x, tx = tid & 15, ty = tid >> 4;
  __shared__ __align__(16) float As[8][132];
  __shared__ __align__(16) float Bs[8][132];
  float acc[8][8] = {};
  int arow = tid >> 1, acol = (tid & 1) * 4;
  int brow = tid >> 5, bcol = (tid & 31) * 4;
  size_t aRowIdx = bm + arow;
  if (MODE == 2) aRowIdx = (size_t)gat[bm + arow];
  const float* aPtr = Ap + aRowIdx * (size_t)K + acol;
  const float* bPtr = Bp + (size_t)brow * N + bn + bcol;

  for (int k0 = k_begin; k0 < k_end; k0 += 8) {
    float4 a4 = *(const float4*)(aPtr + k0);
    float4 b4 = *(const float4*)(bPtr + (size_t)k0 * N);
    __syncthreads();
    As[acol + 0][arow] = a4.x; As[acol + 1][arow] = a4.y;
    As[acol + 2][arow] = a4.z; As[acol + 3][arow] = a4.w;
    *(float4*)&Bs[brow][bcol] = b4;
    __syncthreads();
    #pragma unroll
    for (int kk = 0; kk < 8; ++kk) {
      float av[8], bv[8];
      *(float4*)&av[0] = *(const float4*)&As[kk][ty * 8];
      *(float4*)&av[4] = *(const float4*)&As[kk][ty * 8 + 4];
      *(float4*)&bv[0] = *(const float4*)&Bs[kk][tx * 8];
      *(float4*)&bv[4] = *(const float4*)&Bs[kk][tx * 8 + 4];
      #pragma unroll
      for (int i = 0; i < 8; ++i)
        #pragma unroll
        for (int j = 0; j < 8; ++j)
          acc[i][j] += av[i] * bv[j];
    }
  }

  if (MODE == 0) {
    #pragma unroll
    for (int i = 0; i < 8; ++i) {
      size_t ro = (size_t)(bm + ty * 8 + i) * N + bn + tx * 8;
      #pragma unroll
      for (int j = 0; j < 8; ++j) Cp[ro + j] = acc[i][j];
    }
  } else if (MODE == 1) {
    #pragma unroll
    for (int i = 0; i < 8; ++i) {
      size_t ro = (size_t)(bm + ty * 8 + i) * N + bn + tx * 8;
      #pragma unroll
      for (int j = 0; j < 8; ++j) Cp[ro + j] = acc[i][j] + extra[ro + j];
    }
  } else if (MODE == 2) {
    #pragma unroll
    for (int i = 0; i < 8; ++i) {
      size_t ro = (size_t)(bm + ty * 8 + i) * N + bn + tx * 8;
      #pragma unroll
      for (int j = 0; j < 8; ++j) {
        float vsum = acc[i][j] + bias[bn + tx * 8 + j];
        Cp[ro + j] = 0.5f * vsum * (1.0f + erff(vsum * 0.70710678118654752f));
      }
    }
  } else {  // MODE 3
    int cnt = ecnt[e];
    #pragma unroll
    for (int i = 0; i < 8; ++i) {
      int row = bm + ty * 8 + i;
      if (row < cnt) {
        int tok = gat[row];
        float w = wv[row];
        #pragma unroll
        for (int j = 0; j < 8; ++j) {
          int col = bn + tx * 8 + j;
          float val = acc[i][j];
          if (kc == 0) val += bias[col];
          atomicAdd(&Cp[(size_t)tok * 1024 + col], val * w);
        }
      }
    }
  }
}

// ---------------------------------------------------------------- gate: logits -> softmax -> stable top-2
__global__ __launch_bounds__(256)
void gate_kernel(const float* __restrict__ ffin, const float* __restrict__ Wg,
                 int* __restrict__ te, float* __restrict__ tv) {
  int token = blockIdx.x, tid = threadIdx.x;
  float acc[8] = {};
  const float* xr = ffin + (size_t)token * 1024;
  for (int i = tid; i < 1024; i += 256) {
    float xv = xr[i];
    const float4* wr = (const float4*)&Wg[i * 8];
    float4 w0 = wr[0], w1 = wr[1];
    acc[0] += xv * w0.x; acc[1] += xv * w0.y; acc[2] += xv * w0.z; acc[3] += xv * w0.w;
    acc[4] += xv * w1.x; acc[5] += xv * w1.y; acc[6] += xv * w1.z; acc[7] += xv * w1.w;
  }
  #pragma unroll
  for (int off = 1; off < 64; off <<= 1)
    #pragma unroll
    for (int q = 0; q < 8; ++q) acc[q] += __shfl_xor(acc[q], off);
  __shared__ float red[4][8];
  if ((tid & 63) == 0)
    #pragma unroll
    for (int q = 0; q < 8; ++q) red[tid >> 6][q] = acc[q];
  __syncthreads();
  if (tid == 0) {
    float g[8];
    #pragma unroll
    for (int q = 0; q < 8; ++q) g[q] = red[0][q] + red[1][q] + red[2][q] + red[3][q];
    float mx = g[0];
    #pragma unroll
    for (int q = 1; q < 8; ++q) mx = fmaxf(mx, g[q]);
    float sum = 0.0f;
    #pragma unroll
    for (int q = 0; q < 8; ++q) { g[q] = expf(g[q] - mx); sum += g[q]; }
    float inv = 1.0f / sum;
    #pragma unroll
    for (int q = 0; q < 8; ++q) g[q] *= inv;
    int e1 = 0; float v1 = g[0];
    for (int q = 1; q < 8; ++q) if (g[q] > v1) { v1 = g[q]; e1 = q; }   // ties -> lower idx
    int e2 = -1; float v2 = -1.0f;
    for (int q = 0; q < 8; ++q) { if (q == e1) continue; if (g[q] > v2) { v2 = g[q]; e2 = q; } }
    te[token * 2] = e1; te[token * 2 + 1] = e2;
    tv[token * 2] = v1; tv[token * 2 + 1] = v2;
  }
}

// ---------------------------------------------------------------- per-expert capacity select
// exact jax.lax.top_k semantics: desc by gate value, ties -> lower slot index.
__global__ __launch_bounds__(1024)
void route_sort_kernel(const int* __restrict__ te, const float* __restrict__ tv,
                       int* __restrict__ etok, float* __restrict__ ew,
                       int* __restrict__ ecnt) {
  __shared__ unsigned long long sk[8192];
  int e = blockIdx.x, tid = threadIdx.x;
  for (int s = tid; s < 8192; s += 1024) {
    unsigned long long key = 0ull;
    if (te[s] == e) {
      unsigned vb = __float_as_uint(tv[s]);          // gate > 0 -> positive float, monotone bits
      key = ((unsigned long long)vb << 32) | (unsigned)(0xFFFFFFFFu - (unsigned)s);
    }
    sk[s] = key;
  }
  __syncthreads();
  for (int k = 2; k <= 8192; k <<= 1)
    for (int j = k >> 1; j > 0; j >>= 1) {
      for (int t = tid; t < 4096; t += 1024) {
        int i = ((t & ~(j - 1)) << 1) | (t & (j - 1));
        int p = i | j;
        unsigned long long a = sk[i], b = sk[p];
        bool desc = ((i & k) == 0);
        bool sw = desc ? (a < b) : (a > b);
        if (sw) { sk[i] = b; sk[p] = a; }
      }
      __syncthreads();
    }
  if (tid < 1024) {
    unsigned long long key = sk[tid];
    bool valid = (key != 0ull);
    unsigned slot = 0xFFFFFFFFu - (unsigned)(key & 0xFFFFFFFFull);
    etok[e * 1024 + tid] = valid ? (int)(slot >> 1) : 0;
    ew[e * 1024 + tid] = valid ? __uint_as_float((unsigned)(key >> 32)) : 0.0f;
    unsigned long long nxt = (tid < 1023) ? sk[tid + 1] : 0ull;
    if (!valid && tid == 0) ecnt[e] = 0;
    if (valid && (tid == 1023 || nxt == 0ull)) ecnt[e] = tid + 1;
  }
}

// ---------------------------------------------------------------- init output x + aux
__global__ __launch_bounds__(256)
void copy_init_kernel(const float* __restrict__ src, float* __restrict__ dst,
                      float* __restrict__ aux) {
  size_t gi = (size_t)blockIdx.x * 256 + threadIdx.x;
  ((float4*)dst)[gi] = ((const float4*)src)[gi];
  if (gi == 0) aux[0] = 0.0f;
}

// ================================================================ launch
extern "C" void kernel_launch(void* const* d_in, const int* in_sizes, int n_in,
                              void* d_out, int out_size, void* d_ws, size_t ws_size,
                              hipStream_t stream) {
  const float* x     = (const float*)d_in[0];
  const float* ln1g  = (const float*)d_in[1];
  const float* ln1b  = (const float*)d_in[2];
  const float* ln2g  = (const float*)d_in[3];
  const float* ln2b  = (const float*)d_in[4];
  const float* Wqkv  = (const float*)d_in[5];
  const float* Wproj = (const float*)d_in[6];
  const float* Wg    = (const float*)d_in[7];
  const float* W1    = (const float*)d_in[8];
  const float* b1    = (const float*)d_in[9];
  const float* W2    = (const float*)d_in[10];
  const float* b2    = (const float*)d_in[11];

  float* out_x   = (float*)d_out;                 // 4194304
  float* out_aux = out_x + 4194304;               // 1
  float* out_k   = out_aux + 1;                   // 4194304
  float* out_v   = out_k + 4194304;               // 4194304

  float* ws   = (float*)d_ws;
  float* A    = ws;                               // 4194304  (x_norm -> x_res -> ff_in)
  float* qkv  = ws + 4194304;                     // 12582912
  float* o    = ws + 16777216;                    // 4194304  (attn out -> h reuse)
  float* st   = ws + 20971520;                    // 65536
  float* ct   = st + 65536;                       // 65536
  int*   te   = (int*)(ct + 65536);               // 8192
  float* tv   = (float*)(te + 8192);              // 8192
  int*   etok = (int*)(tv + 8192);                // 8192
  float* ew   = (float*)(etok + 8192);            // 8192
  int*   ecnt = (int*)(ew + 8192);                // 8
  float* h    = o;                                // expert hidden, 1024x4096, reuses o

  // LN1
  ln_kernel<<<NTOK, 256, 0, stream>>>(x, ln1g, ln1b, A);
  // RoPE tables (f64)
  sincos_kernel<<<TT, 32, 0, stream>>>(st, ct);
  // QKV = x_norm @ Wqkv  (4096 x 3072 x 1024)
  sgemm_kernel<0><<<dim3(24, 32), 256, 0, stream>>>(A, Wqkv, qkv, nullptr, nullptr, nullptr, nullptr,
                                                    4096, 3072, 1024, 0, 1, 0);
  // RoPE + emit k, v outputs
  rope_kernel<<<NTOK, 256, 0, stream>>>(qkv, st, ct, out_k, out_v);
  // causal attention
  flash_kernel<<<dim3(32, 16, 2), 256, 0, stream>>>(qkv, o);
  // x_res = o @ Wproj + x   (writes into A; x_norm dead)
  sgemm_kernel<1><<<dim3(8, 32), 256, 0, stream>>>(o, Wproj, A, x, nullptr, nullptr, nullptr,
                                                   4096, 1024, 1024, 0, 1, 0);
  // out.x = x_res; aux = 0
  copy_init_kernel<<<4096, 256, 0, stream>>>(A, out_x, out_aux);
  // ff_in = LN2(x_res) in place
  ln_kernel<<<NTOK, 256, 0, stream>>>(A, ln2g, ln2b, A);
  // gating
  gate_kernel<<<NTOK, 256, 0, stream>>>(A, Wg, te, tv);
  route_sort_kernel<<<8, 1024, 0, stream>>>(te, tv, etok, ew, ecnt);
  // experts (sequential; h reuses o buffer)
  for (int e = 0; e < 8; ++e) {
    sgemm_kernel<2><<<dim3(32, 8), 256, 0, stream>>>(A, W1, h, b1, etok, nullptr, nullptr,
                                                     1024, 4096, 1024, e, 1, 0);
    sgemm_kernel<3><<<dim3(8, 8, 4), 256, 0, stream>>>(h, W2, out_x, b2, etok, ew, ecnt,
                                                       1024, 1024, 4096, e, 4, 0);
  }
}

// Round 2
// 1833.613 us; speedup vs baseline: 3.0318x; 3.0318x over previous
//
#include <hip/hip_runtime.h>
#include <hip/hip_bf16.h>
#include <math.h>

// Round 2: bf16-MFMA GEMMs (split-bf16 for the routing-critical path), flash v2
// (LDS-P PV, swizzled conflict-free tiles), deterministic MoE combine.
// B=2 T=2048 D=1024 NH=16 HD=64 HALF=32 NEXP=8 TOPK=2 CAP=1024 FF=4096

#define TT 2048
#define NTOK 4096

typedef __attribute__((ext_vector_type(8))) short bf16x8;
typedef __attribute__((ext_vector_type(4))) float f32x4;

static __device__ __forceinline__ ushort f2bf(float f) {
  union { float f; unsigned u; } v; v.f = f;
  unsigned r = v.u + 0x7FFFu + ((v.u >> 16) & 1u);
  return (ushort)(r >> 16);
}
static __device__ __forceinline__ float bf2f(ushort h) {
  union { unsigned u; float f; } v; v.u = ((unsigned)h) << 16; return v.f;
}

// ---------------------------------------------------------------- LayerNorm
__global__ __launch_bounds__(256)
void ln_kernel(const float* __restrict__ x, const float* __restrict__ g,
               const float* __restrict__ b, float* __restrict__ out) {
  int row = blockIdx.x, tid = threadIdx.x;
  const float4* xr = (const float4*)(x + (size_t)row * 1024);
  float4 v = xr[tid];
  float s = v.x + v.y + v.z + v.w;
  #pragma unroll
  for (int off = 1; off < 64; off <<= 1) s += __shfl_xor(s, off);
  __shared__ float red1[4], red2[4];
  if ((tid & 63) == 0) red1[tid >> 6] = s;
  __syncthreads();
  float mu = (red1[0] + red1[1] + red1[2] + red1[3]) * (1.0f / 1024.0f);
  float dx = v.x - mu, dy = v.y - mu, dz = v.z - mu, dw = v.w - mu;
  float ss = dx*dx + dy*dy + dz*dz + dw*dw;
  #pragma unroll
  for (int off = 1; off < 64; off <<= 1) ss += __shfl_xor(ss, off);
  if ((tid & 63) == 0) red2[tid >> 6] = ss;
  __syncthreads();
  float var = (red2[0] + red2[1] + red2[2] + red2[3]) * (1.0f / 1024.0f);
  float inv = 1.0f / sqrtf(var + 1e-5f);
  float4 g4 = ((const float4*)g)[tid];
  float4 b4 = ((const float4*)b)[tid];
  float4 o4;
  o4.x = dx * inv * g4.x + b4.x;
  o4.y = dy * inv * g4.y + b4.y;
  o4.z = dz * inv * g4.z + b4.z;
  o4.w = dw * inv * g4.w + b4.w;
  ((float4*)(out + (size_t)row * 1024))[tid] = o4;
}

// ---------------------------------------------------------------- RoPE tables (f64)
__global__ void sincos_kernel(float* __restrict__ st, float* __restrict__ ct) {
  int t = blockIdx.x, j = threadIdx.x;
  double invf = pow(10000.0, -((double)(2 * j)) / 64.0);
  double ang = (double)t * invf;
  st[t * 32 + j] = (float)sin(ang);
  ct[t * 32 + j] = (float)cos(ang);
}

// ---------------------------------------------------------------- RoPE apply + k,v outputs
__global__ __launch_bounds__(256)
void rope_kernel(float* __restrict__ qkv, const float* __restrict__ st,
                 const float* __restrict__ ct, float* __restrict__ kout,
                 float* __restrict__ vout) {
  int row = blockIdx.x;
  int t = row & (TT - 1);
  int tid = threadIdx.x;
  float* base = qkv + (size_t)row * 3072;
  #pragma unroll
  for (int l = 0; l < 2; ++l) {
    int idx = l * 256 + tid;
    int h = idx >> 5, j = idx & 31;
    float s = st[t * 32 + j], c = ct[t * 32 + j];
    float* qp = base + h * 192;
    float q1 = qp[j], q2 = qp[j + 32];
    qp[j]      = q1 * c - q2 * s;
    qp[j + 32] = q1 * s + q2 * c;
    float k1 = qp[64 + j], k2 = qp[96 + j];
    float kr1 = k1 * c - k2 * s, kr2 = k1 * s + k2 * c;
    qp[64 + j] = kr1; qp[96 + j] = kr2;
    kout[(size_t)row * 1024 + h * 64 + j]      = kr1;
    kout[(size_t)row * 1024 + h * 64 + 32 + j] = kr2;
  }
  #pragma unroll
  for (int l = 0; l < 4; ++l) {
    int f = l * 256 + tid;
    int h = f >> 6, d = f & 63;
    vout[(size_t)row * 1024 + f] = base[h * 192 + 128 + d];
  }
}

// ---------------------------------------------------------------- flash attention v2 (fp32)
// stride-64 tiles + XOR chunk swizzle (conflict-free), PV via LDS P tile.
#define SWF(tile, row, ch) ((tile) + ((row) << 6) + ((((ch) ^ (((row) >> 2) & 15))) << 2))
__global__ __launch_bounds__(256)
void flash2_kernel(const float* __restrict__ qkv, float* __restrict__ o) {
  __shared__ float Qs[64 * 64], Ks[64 * 64], Vs[64 * 64], Ps[64 * 64];
  int qt = gridDim.x - 1 - blockIdx.x;          // long blocks launch first
  int h = blockIdx.y, b = blockIdx.z;
  int tid = threadIdx.x;
  int i4 = tid >> 4, j4 = tid & 15;
  int iR = i4 * 4, jC = j4 * 4;
  size_t bT = (size_t)b * TT;
  int q0 = qt * 64;
  #pragma unroll
  for (int l = 0; l < 4; ++l) {
    int idx = l * 256 + tid;
    int r = idx >> 4, ch = idx & 15;
    *(float4*)SWF(Qs, r, ch) = *(const float4*)&qkv[(bT + q0 + r) * 3072 + h * 192 + ch * 4];
  }
  float accO[4][4] = {};
  float mrow[4] = {-3.402823466e38f, -3.402823466e38f, -3.402823466e38f, -3.402823466e38f};
  float lrow[4] = {};
  for (int kt = 0; kt <= qt; ++kt) {
    __syncthreads();
    #pragma unroll
    for (int l = 0; l < 4; ++l) {
      int idx = l * 256 + tid;
      int r = idx >> 4, ch = idx & 15;
      size_t gb = (bT + kt * 64 + r) * 3072 + h * 192;
      *(float4*)SWF(Ks, r, ch) = *(const float4*)&qkv[gb + 64 + ch * 4];
      *(float4*)SWF(Vs, r, ch) = *(const float4*)&qkv[gb + 128 + ch * 4];
    }
    __syncthreads();
    float s[4][4] = {};
    #pragma unroll
    for (int d4 = 0; d4 < 16; ++d4) {
      float4 qv[4], kv[4];
      #pragma unroll
      for (int r = 0; r < 4; ++r) qv[r] = *(const float4*)SWF(Qs, iR + r, d4);
      #pragma unroll
      for (int c = 0; c < 4; ++c) kv[c] = *(const float4*)SWF(Ks, jC + c, d4);
      #pragma unroll
      for (int r = 0; r < 4; ++r)
        #pragma unroll
        for (int c = 0; c < 4; ++c)
          s[r][c] += qv[r].x * kv[c].x + qv[r].y * kv[c].y + qv[r].z * kv[c].z + qv[r].w * kv[c].w;
    }
    #pragma unroll
    for (int r = 0; r < 4; ++r)
      #pragma unroll
      for (int c = 0; c < 4; ++c) {
        float sv = s[r][c] * 0.125f;
        if (kt * 64 + jC + c > q0 + iR + r) sv = -3.402823466e38f;
        s[r][c] = sv;
      }
    #pragma unroll
    for (int r = 0; r < 4; ++r) {
      float rm = fmaxf(fmaxf(s[r][0], s[r][1]), fmaxf(s[r][2], s[r][3]));
      #pragma unroll
      for (int off = 1; off < 16; off <<= 1) rm = fmaxf(rm, __shfl_xor(rm, off));
      float mnew = fmaxf(mrow[r], rm);
      float f = expf(mrow[r] - mnew);
      float psum = 0.0f;
      #pragma unroll
      for (int c = 0; c < 4; ++c) { float p = expf(s[r][c] - mnew); s[r][c] = p; psum += p; }
      #pragma unroll
      for (int off = 1; off < 16; off <<= 1) psum += __shfl_xor(psum, off);
      lrow[r] = lrow[r] * f + psum;
      mrow[r] = mnew;
      #pragma unroll
      for (int c = 0; c < 4; ++c) accO[r][c] *= f;
    }
    #pragma unroll
    for (int r = 0; r < 4; ++r) {
      float4 pv = {s[r][0], s[r][1], s[r][2], s[r][3]};
      *(float4*)SWF(Ps, iR + r, j4) = pv;
    }
    __syncthreads();
    #pragma unroll
    for (int jb = 0; jb < 16; ++jb) {
      float4 p[4], vv[4];
      #pragma unroll
      for (int r = 0; r < 4; ++r) p[r] = *(const float4*)SWF(Ps, iR + r, jb);
      #pragma unroll
      for (int c = 0; c < 4; ++c) vv[c] = *(const float4*)SWF(Vs, jb * 4 + c, j4);
      #pragma unroll
      for (int r = 0; r < 4; ++r) {
        accO[r][0] += p[r].x * vv[0].x + p[r].y * vv[1].x + p[r].z * vv[2].x + p[r].w * vv[3].x;
        accO[r][1] += p[r].x * vv[0].y + p[r].y * vv[1].y + p[r].z * vv[2].y + p[r].w * vv[3].y;
        accO[r][2] += p[r].x * vv[0].z + p[r].y * vv[1].z + p[r].z * vv[2].z + p[r].w * vv[3].z;
        accO[r][3] += p[r].x * vv[0].w + p[r].y * vv[1].w + p[r].z * vv[2].w + p[r].w * vv[3].w;
      }
    }
  }
  #pragma unroll
  for (int r = 0; r < 4; ++r) {
    float inv = 1.0f / lrow[r];
    float4 o4 = {accO[r][0] * inv, accO[r][1] * inv, accO[r][2] * inv, accO[r][3] * inv};
    *(float4*)&o[(bT + q0 + iR + r) * 1024 + h * 64 + jC] = o4;
  }
}

// ---------------------------------------------------------------- transpose + bf16 convert (+lo split)
template<bool LO>
__global__ void tconv_kernel(const float* __restrict__ in, ushort* __restrict__ oh,
                             ushort* __restrict__ ol, int K, int N) {
  __shared__ float t[32][33];
  int z = blockIdx.z;
  const float* ip = in + (size_t)z * K * N;
  ushort* ohp = oh + (size_t)z * K * N;
  ushort* olp = LO ? (ol + (size_t)z * K * N) : nullptr;
  int n0 = blockIdx.x * 32, k0 = blockIdx.y * 32;
  int tx = threadIdx.x, ty = threadIdx.y;   // (32,8)
  #pragma unroll
  for (int i = 0; i < 4; ++i)
    t[ty + 8 * i][tx] = ip[(size_t)(k0 + ty + 8 * i) * N + n0 + tx];
  __syncthreads();
  #pragma unroll
  for (int i = 0; i < 4; ++i) {
    float v = t[tx][ty + 8 * i];
    size_t off = (size_t)(n0 + ty + 8 * i) * K + k0 + tx;
    ushort hb = f2bf(v);
    ohp[off] = hb;
    if (LO) olp[off] = f2bf(v - bf2f(hb));
  }
}

// ---------------------------------------------------------------- rowwise hi/lo bf16 split
__global__ __launch_bounds__(256)
void split_kernel(const float* __restrict__ in, ushort* __restrict__ oh,
                  ushort* __restrict__ ol) {
  size_t i = ((size_t)blockIdx.x * 256 + threadIdx.x) * 4;
  float4 v = *(const float4*)(in + i);
  ushort h0 = f2bf(v.x), h1 = f2bf(v.y), h2 = f2bf(v.z), h3 = f2bf(v.w);
  ushort4 hh = {h0, h1, h2, h3};
  *(ushort4*)(oh + i) = hh;
  ushort4 ll = {f2bf(v.x - bf2f(h0)), f2bf(v.y - bf2f(h1)),
                f2bf(v.z - bf2f(h2)), f2bf(v.w - bf2f(h3))};
  *(ushort4*)(ol + i) = ll;
}

// ---------------------------------------------------------------- MFMA GEMM
// C[M][N] = A[M][K] @ B^T[N][K]  (bf16 in, fp32 acc). 128x128 tile, 4 waves.
// SPLIT3: logical K' = 3K over segments (Ah,Bh),(Ah,Bl),(Al,Bh).
// EPI: 0 fp32 C; 1 fp32 C+extra; 2 bf16 gelu(C+bias); 3 bf16 C+bias.
#define LOAD_STEP(tt) do {                                                     \
    int seg = SPLIT3 ? ((tt) / kPer) : 0;                                      \
    int kk = (SPLIT3 ? ((tt) % kPer) : (tt)) << 6;                             \
    const ushort* Ause = (SPLIT3 && seg == 2) ? AlB : AhB;                     \
    const ushort* Buse = (SPLIT3 && seg == 1) ? BlB : BhB;                     \
    _Pragma("unroll")                                                          \
    for (int q = 0; q < 4; ++q) {                                              \
      int rr = r0 + 32 * q;                                                    \
      int clog = cph ^ (rr & 7);                                               \
      ra[q] = *(const bf16x8*)(Ause + (size_t)garow[q] * K + kk + clog * 8);   \
      rb[q] = *(const bf16x8*)(Buse + (size_t)(bn + rr) * K + kk + clog * 8);  \
    }                                                                          \
  } while (0)

template<int EPI, bool GATHER, bool SPLIT3>
__global__ __launch_bounds__(256, 2)
void mgemm(const ushort* __restrict__ Ah, const ushort* __restrict__ Al,
           const ushort* __restrict__ Bh, const ushort* __restrict__ Bl,
           void* __restrict__ Cv, const float* __restrict__ extra,
           const int* __restrict__ gatAll, int N, int K,
           long aEStride, long bEStride, long cEStride, int biasEStride) {
  __shared__ ushort As[128 * 64];
  __shared__ ushort Bs[128 * 64];
  int z = blockIdx.z;
  const ushort* AhB = Ah + (size_t)z * aEStride;
  const ushort* AlB = SPLIT3 ? (Al + (size_t)z * aEStride) : nullptr;
  const ushort* BhB = Bh + (size_t)z * bEStride;
  const ushort* BlB = SPLIT3 ? (Bl + (size_t)z * bEStride) : nullptr;
  const int* gat = GATHER ? (gatAll + z * 1024) : nullptr;
  int bm = blockIdx.y * 128, bn = blockIdx.x * 128;
  int tid = threadIdx.x;
  int r0 = tid >> 3, cph = tid & 7;
  int garow[4];
  #pragma unroll
  for (int q = 0; q < 4; ++q) {
    int rr = r0 + 32 * q;
    garow[q] = GATHER ? gat[bm + rr] : (bm + rr);
  }
  int kPer = K >> 6;
  int kSteps = (SPLIT3 ? 3 : 1) * kPer;
  int wid = tid >> 6, lane = tid & 63;
  int wm = wid >> 1, wn = wid & 1;
  int lr = lane & 15, lk = lane >> 4;
  f32x4 acc[4][4] = {};
  bf16x8 ra[4], rb[4];
  LOAD_STEP(0);
  for (int t = 0; t < kSteps; ++t) {
    __syncthreads();
    #pragma unroll
    for (int q = 0; q < 4; ++q) {
      int rr = r0 + 32 * q;
      *(bf16x8*)&As[rr * 64 + cph * 8] = ra[q];
      *(bf16x8*)&Bs[rr * 64 + cph * 8] = rb[q];
    }
    __syncthreads();
    if (t + 1 < kSteps) LOAD_STEP(t + 1);
    #pragma unroll
    for (int kh = 0; kh < 2; ++kh) {
      bf16x8 af[4], bfr[4];
      #pragma unroll
      for (int mf = 0; mf < 4; ++mf) {
        int row = wm * 64 + mf * 16 + lr;
        int ch = (kh * 4 + lk) ^ (row & 7);
        af[mf] = *(const bf16x8*)&As[row * 64 + ch * 8];
      }
      #pragma unroll
      for (int nf = 0; nf < 4; ++nf) {
        int row = wn * 64 + nf * 16 + lr;
        int ch = (kh * 4 + lk) ^ (row & 7);
        bfr[nf] = *(const bf16x8*)&Bs[row * 64 + ch * 8];
      }
      #pragma unroll
      for (int mf = 0; mf < 4; ++mf)
        #pragma unroll
        for (int nf = 0; nf < 4; ++nf)
          acc[mf][nf] = __builtin_amdgcn_mfma_f32_16x16x32_bf16(af[mf], bfr[nf], acc[mf][nf], 0, 0, 0);
    }
  }
  int crow = bm + wm * 64, ccol = bn + wn * 64;
  if constexpr (EPI <= 1) {
    float* C = (float*)Cv;
    #pragma unroll
    for (int mf = 0; mf < 4; ++mf)
      #pragma unroll
      for (int nf = 0; nf < 4; ++nf)
        #pragma unroll
        for (int r = 0; r < 4; ++r) {
          int row = crow + mf * 16 + lk * 4 + r;
          int col = ccol + nf * 16 + lr;
          float v = acc[mf][nf][r];
          if constexpr (EPI == 1) v += extra[(size_t)row * N + col];
          C[(size_t)row * N + col] = v;
        }
  } else {
    const float* bias = extra + (size_t)z * biasEStride;
    ushort* C = (ushort*)Cv + (size_t)z * cEStride;
    #pragma unroll
    for (int mf = 0; mf < 4; ++mf)
      #pragma unroll
      for (int nf = 0; nf < 4; ++nf)
        #pragma unroll
        for (int r = 0; r < 4; ++r) {
          int row = crow + mf * 16 + lk * 4 + r;
          int col = ccol + nf * 16 + lr;
          float v = acc[mf][nf][r] + bias[col];
          if constexpr (EPI == 2)
            v = 0.5f * v * (1.0f + erff(v * 0.70710678118654752f));
          C[(size_t)row * N + col] = f2bf(v);
        }
  }
}

// ---------------------------------------------------------------- gate: softmax + stable top-2
__global__ __launch_bounds__(256)
void gate_kernel(const float* __restrict__ ffin, const float* __restrict__ Wg,
                 int* __restrict__ te, float* __restrict__ tv, int* __restrict__ inv) {
  int token = blockIdx.x, tid = threadIdx.x;
  float acc[8] = {};
  const float* xr = ffin + (size_t)token * 1024;
  for (int i = tid; i < 1024; i += 256) {
    float xv = xr[i];
    const float4* wr = (const float4*)&Wg[i * 8];
    float4 w0 = wr[0], w1 = wr[1];
    acc[0] += xv * w0.x; acc[1] += xv * w0.y; acc[2] += xv * w0.z; acc[3] += xv * w0.w;
    acc[4] += xv * w1.x; acc[5] += xv * w1.y; acc[6] += xv * w1.z; acc[7] += xv * w1.w;
  }
  #pragma unroll
  for (int off = 1; off < 64; off <<= 1)
    #pragma unroll
    for (int q = 0; q < 8; ++q) acc[q] += __shfl_xor(acc[q], off);
  __shared__ float red[4][8];
  if ((tid & 63) == 0)
    #pragma unroll
    for (int q = 0; q < 8; ++q) red[tid >> 6][q] = acc[q];
  __syncthreads();
  if (tid == 0) {
    float g[8];
    #pragma unroll
    for (int q = 0; q < 8; ++q) g[q] = red[0][q] + red[1][q] + red[2][q] + red[3][q];
    float mx = g[0];
    #pragma unroll
    for (int q = 1; q < 8; ++q) mx = fmaxf(mx, g[q]);
    float sum = 0.0f;
    #pragma unroll
    for (int q = 0; q < 8; ++q) { g[q] = expf(g[q] - mx); sum += g[q]; }
    float inv_s = 1.0f / sum;
    #pragma unroll
    for (int q = 0; q < 8; ++q) g[q] *= inv_s;
    int e1 = 0; float v1 = g[0];
    for (int q = 1; q < 8; ++q) if (g[q] > v1) { v1 = g[q]; e1 = q; }
    int e2 = -1; float v2 = -1.0f;
    for (int q = 0; q < 8; ++q) { if (q == e1) continue; if (g[q] > v2) { v2 = g[q]; e2 = q; } }
    te[token * 2] = e1; te[token * 2 + 1] = e2;
    tv[token * 2] = v1; tv[token * 2 + 1] = v2;
    inv[token * 2] = -1; inv[token * 2 + 1] = -1;
  }
}

// ---------------------------------------------------------------- per-expert capacity select
__global__ __launch_bounds__(1024)
void route_sort_kernel(const int* __restrict__ te, const float* __restrict__ tv,
                       int* __restrict__ etok, float* __restrict__ ew,
                       int* __restrict__ inv) {
  __shared__ unsigned long long sk[8192];
  int e = blockIdx.x, tid = threadIdx.x;
  for (int s = tid; s < 8192; s += 1024) {
    unsigned long long key = 0ull;
    if (te[s] == e) {
      unsigned vb = __float_as_uint(tv[s]);
      key = ((unsigned long long)vb << 32) | (unsigned)(0xFFFFFFFFu - (unsigned)s);
    }
    sk[s] = key;
  }
  __syncthreads();
  for (int k = 2; k <= 8192; k <<= 1)
    for (int j = k >> 1; j > 0; j >>= 1) {
      for (int t = tid; t < 4096; t += 1024) {
        int i = ((t & ~(j - 1)) << 1) | (t & (j - 1));
        int p = i | j;
        unsigned long long a = sk[i], bq = sk[p];
        bool desc = ((i & k) == 0);
        bool sw = desc ? (a < bq) : (a > bq);
        if (sw) { sk[i] = bq; sk[p] = a; }
      }
      __syncthreads();
    }
  if (tid < 1024) {
    unsigned long long key = sk[tid];
    bool valid = (key != 0ull);
    unsigned slot = 0xFFFFFFFFu - (unsigned)(key & 0xFFFFFFFFull);
    etok[e * 1024 + tid] = valid ? (int)(slot >> 1) : 0;
    ew[e * 1024 + tid] = valid ? __uint_as_float((unsigned)(key >> 32)) : 0.0f;
    if (valid) inv[slot] = e * 1024 + tid;
  }
}

// ---------------------------------------------------------------- final combine (deterministic)
__global__ __launch_bounds__(256)
void combine_kernel(const float* __restrict__ xres, const ushort* __restrict__ eo,
                    const int* __restrict__ inv, const float* __restrict__ ew,
                    float* __restrict__ outx, float* __restrict__ aux) {
  int token = blockIdx.x;
  int d = threadIdx.x * 4;
  float4 acc = *(const float4*)&xres[(size_t)token * 1024 + d];
  #pragma unroll
  for (int j = 0; j < 2; ++j) {
    int p = inv[token * 2 + j];
    if (p >= 0) {
      float w = ew[p];
      const ushort* ep = eo + (size_t)p * 1024 + d;
      acc.x += w * bf2f(ep[0]); acc.y += w * bf2f(ep[1]);
      acc.z += w * bf2f(ep[2]); acc.w += w * bf2f(ep[3]);
    }
  }
  *(float4*)&outx[(size_t)token * 1024 + d] = acc;
  if (token == 0 && threadIdx.x == 0) aux[0] = 0.0f;
}

// ================================================================ launch
extern "C" void kernel_launch(void* const* d_in, const int* in_sizes, int n_in,
                              void* d_out, int out_size, void* d_ws, size_t ws_size,
                              hipStream_t stream) {
  const float* x     = (const float*)d_in[0];
  const float* ln1g  = (const float*)d_in[1];
  const float* ln1b  = (const float*)d_in[2];
  const float* ln2g  = (const float*)d_in[3];
  const float* ln2b  = (const float*)d_in[4];
  const float* Wqkv  = (const float*)d_in[5];
  const float* Wproj = (const float*)d_in[6];
  const float* Wg    = (const float*)d_in[7];
  const float* W1    = (const float*)d_in[8];
  const float* b1    = (const float*)d_in[9];
  const float* W2    = (const float*)d_in[10];
  const float* b2    = (const float*)d_in[11];

  float* out_x   = (float*)d_out;
  float* out_aux = out_x + 4194304;
  float* out_k   = out_aux + 1;
  float* out_v   = out_k + 4194304;

  float* ws   = (float*)d_ws;
  float* A    = ws;                          // x_norm -> x_res
  float* qkvb = ws + 4194304;                // fp32 qkv (aliased by h later)
  float* o    = ws + 16777216;               // attn out -> ff_in
  float* st   = ws + 20971520;
  float* ct   = ws + 21037056;
  int*   te   = (int*)(ws + 21102592);
  float* tv   = ws + 21110784;
  int*   etok = (int*)(ws + 21118976);
  float* ew   = ws + 21127168;
  int*   inv  = (int*)(ws + 21135360);
  ushort* bfAh = (ushort*)(ws + 21143552);   // [4096][1024] bf16
  ushort* bfAl = (ushort*)(ws + 23240704);
  ushort* BqH  = (ushort*)(ws + 25337856);   // WqkvT hi [3072][1024]
  ushort* BqL  = (ushort*)(ws + 26910720);
  ushort* BpH  = (ushort*)(ws + 28483584);   // WprojT hi [1024][1024]
  ushort* BpL  = (ushort*)(ws + 29007872);
  ushort* W1t  = (ushort*)(ws + 29532160);   // [8][4096][1024]
  ushort* W2t  = (ushort*)(ws + 46309376);   // [8][1024][4096]
  ushort* eo   = (ushort*)(ws + 63086592);   // [8192][1024] bf16
  ushort* hbuf = (ushort*)(ws + 4194304);    // [8][1024][4096] bf16, aliases qkvb+o

  // weight prep (independent of activations)
  tconv_kernel<true ><<<dim3(96, 32, 1),  dim3(32, 8), 0, stream>>>(Wqkv,  BqH, BqL, 1024, 3072);
  tconv_kernel<true ><<<dim3(32, 32, 1),  dim3(32, 8), 0, stream>>>(Wproj, BpH, BpL, 1024, 1024);
  tconv_kernel<false><<<dim3(128, 32, 8), dim3(32, 8), 0, stream>>>(W1, W1t, nullptr, 1024, 4096);
  tconv_kernel<false><<<dim3(32, 128, 8), dim3(32, 8), 0, stream>>>(W2, W2t, nullptr, 4096, 1024);
  sincos_kernel<<<TT, 32, 0, stream>>>(st, ct);

  // LN1 + split
  ln_kernel<<<NTOK, 256, 0, stream>>>(x, ln1g, ln1b, A);
  split_kernel<<<4096, 256, 0, stream>>>(A, bfAh, bfAl);
  // QKV (split-bf16, K' = 3*1024)
  mgemm<0, false, true><<<dim3(24, 32, 1), 256, 0, stream>>>(
      bfAh, bfAl, BqH, BqL, qkvb, nullptr, nullptr, 3072, 1024, 0, 0, 0, 0);
  rope_kernel<<<NTOK, 256, 0, stream>>>(qkvb, st, ct, out_k, out_v);
  flash2_kernel<<<dim3(32, 16, 2), 256, 0, stream>>>(qkvb, o);
  // proj + residual (split-bf16)
  split_kernel<<<4096, 256, 0, stream>>>(o, bfAh, bfAl);
  mgemm<1, false, true><<<dim3(8, 32, 1), 256, 0, stream>>>(
      bfAh, bfAl, BpH, BpL, A, x, nullptr, 1024, 1024, 0, 0, 0, 0);
  // LN2 -> ff_in (in o buffer), gate, route
  ln_kernel<<<NTOK, 256, 0, stream>>>(A, ln2g, ln2b, o);
  gate_kernel<<<NTOK, 256, 0, stream>>>(o, Wg, te, tv, inv);
  split_kernel<<<4096, 256, 0, stream>>>(o, bfAh, bfAl);   // ffin bf16 (hi used)
  route_sort_kernel<<<8, 1024, 0, stream>>>(te, tv, etok, ew, inv);
  // experts: up (gather + gelu -> bf16 h), down (-> bf16 eo)
  mgemm<2, true, false><<<dim3(32, 8, 8), 256, 0, stream>>>(
      bfAh, nullptr, W1t, nullptr, hbuf, b1, etok, 4096, 1024,
      0, 4096L * 1024, 1024L * 4096, 4096);
  mgemm<3, false, false><<<dim3(8, 8, 8), 256, 0, stream>>>(
      hbuf, nullptr, W2t, nullptr, eo, b2, nullptr, 1024, 4096,
      1024L * 4096, 1024L * 4096, 1024L * 1024, 1024);
  combine_kernel<<<NTOK, 256, 0, stream>>>(A, eo, inv, ew, out_x, out_aux);
}

// Round 3
// 838.126 us; speedup vs baseline: 6.6329x; 2.1878x over previous
//
#include <hip/hip_runtime.h>
#include <hip/hip_bf16.h>
#include <math.h>

// Round 3: MFMA flash attention (split-bf16 3-term, swapped-QK, in-register P
// redistribution, LDS-transposed V). GEMMs unchanged from round 2.
// B=2 T=2048 D=1024 NH=16 HD=64 HALF=32 NEXP=8 TOPK=2 CAP=1024 FF=4096

#define TT 2048
#define NTOK 4096

typedef __attribute__((ext_vector_type(8))) short bf16x8;
typedef __attribute__((ext_vector_type(4))) float f32x4;

static __device__ __forceinline__ ushort f2bf(float f) {
  union { float f; unsigned u; } v; v.f = f;
  unsigned r = v.u + 0x7FFFu + ((v.u >> 16) & 1u);
  return (ushort)(r >> 16);
}
static __device__ __forceinline__ float bf2f(ushort h) {
  union { unsigned u; float f; } v; v.u = ((unsigned)h) << 16; return v.f;
}

// ---------------------------------------------------------------- LayerNorm
__global__ __launch_bounds__(256)
void ln_kernel(const float* __restrict__ x, const float* __restrict__ g,
               const float* __restrict__ b, float* __restrict__ out) {
  int row = blockIdx.x, tid = threadIdx.x;
  const float4* xr = (const float4*)(x + (size_t)row * 1024);
  float4 v = xr[tid];
  float s = v.x + v.y + v.z + v.w;
  #pragma unroll
  for (int off = 1; off < 64; off <<= 1) s += __shfl_xor(s, off);
  __shared__ float red1[4], red2[4];
  if ((tid & 63) == 0) red1[tid >> 6] = s;
  __syncthreads();
  float mu = (red1[0] + red1[1] + red1[2] + red1[3]) * (1.0f / 1024.0f);
  float dx = v.x - mu, dy = v.y - mu, dz = v.z - mu, dw = v.w - mu;
  float ss = dx*dx + dy*dy + dz*dz + dw*dw;
  #pragma unroll
  for (int off = 1; off < 64; off <<= 1) ss += __shfl_xor(ss, off);
  if ((tid & 63) == 0) red2[tid >> 6] = ss;
  __syncthreads();
  float var = (red2[0] + red2[1] + red2[2] + red2[3]) * (1.0f / 1024.0f);
  float inv = 1.0f / sqrtf(var + 1e-5f);
  float4 g4 = ((const float4*)g)[tid];
  float4 b4 = ((const float4*)b)[tid];
  float4 o4;
  o4.x = dx * inv * g4.x + b4.x;
  o4.y = dy * inv * g4.y + b4.y;
  o4.z = dz * inv * g4.z + b4.z;
  o4.w = dw * inv * g4.w + b4.w;
  ((float4*)(out + (size_t)row * 1024))[tid] = o4;
}

// ---------------------------------------------------------------- RoPE tables (f64)
__global__ void sincos_kernel(float* __restrict__ st, float* __restrict__ ct) {
  int t = blockIdx.x, j = threadIdx.x;
  double invf = pow(10000.0, -((double)(2 * j)) / 64.0);
  double ang = (double)t * invf;
  st[t * 32 + j] = (float)sin(ang);
  ct[t * 32 + j] = (float)cos(ang);
}

// ---------------------------------------------------------------- RoPE apply + k,v outputs
__global__ __launch_bounds__(256)
void rope_kernel(float* __restrict__ qkv, const float* __restrict__ st,
                 const float* __restrict__ ct, float* __restrict__ kout,
                 float* __restrict__ vout) {
  int row = blockIdx.x;
  int t = row & (TT - 1);
  int tid = threadIdx.x;
  float* base = qkv + (size_t)row * 3072;
  #pragma unroll
  for (int l = 0; l < 2; ++l) {
    int idx = l * 256 + tid;
    int h = idx >> 5, j = idx & 31;
    float s = st[t * 32 + j], c = ct[t * 32 + j];
    float* qp = base + h * 192;
    float q1 = qp[j], q2 = qp[j + 32];
    qp[j]      = q1 * c - q2 * s;
    qp[j + 32] = q1 * s + q2 * c;
    float k1 = qp[64 + j], k2 = qp[96 + j];
    float kr1 = k1 * c - k2 * s, kr2 = k1 * s + k2 * c;
    qp[64 + j] = kr1; qp[96 + j] = kr2;
    kout[(size_t)row * 1024 + h * 64 + j]      = kr1;
    kout[(size_t)row * 1024 + h * 64 + 32 + j] = kr2;
  }
  #pragma unroll
  for (int l = 0; l < 4; ++l) {
    int f = l * 256 + tid;
    int h = f >> 6, d = f & 63;
    vout[(size_t)row * 1024 + f] = base[h * 192 + 128 + d];
  }
}

// ---------------------------------------------------------------- flash attention v3 (MFMA, split-bf16)
// wg = 4 waves, QBLK=64 (16 q-rows/wave), KVBLK=64.
// S^T = mfma(K, Q^T): lane group (lr, lk=0..3) owns q-row lr; kv = mf*16+lk*4+r.
// PV: O = mfma(P, Vt): P A-frags assembled in-register via shfl.
__global__ __launch_bounds__(256, 3)
void flash3_kernel(const float* __restrict__ qkv, float* __restrict__ o) {
  __shared__ ushort Kh[64 * 64], Kl[64 * 64], Vth[64 * 64], Vtl[64 * 64];
  __shared__ float Vf[64 * 64];
  int qt = gridDim.x - 1 - blockIdx.x;          // long blocks first
  int h = blockIdx.y, b = blockIdx.z;
  int tid = threadIdx.x;
  int w = tid >> 6, lane = tid & 63;
  int lr = lane & 15, lk = lane >> 4;
  size_t bT = (size_t)b * TT;
  int q0 = qt * 64;
  int qg = q0 + w * 16 + lr;                    // this lane's q-row
  // Q fragments (B-operand): d = kst*32 + lk*8 + j
  bf16x8 qh[2], ql[2];
  {
    const float* qp = qkv + (bT + qg) * 3072 + h * 192;
    #pragma unroll
    for (int kst = 0; kst < 2; ++kst) {
      float4 a = *(const float4*)(qp + kst * 32 + lk * 8);
      float4 bq = *(const float4*)(qp + kst * 32 + lk * 8 + 4);
      float vals[8] = {a.x, a.y, a.z, a.w, bq.x, bq.y, bq.z, bq.w};
      union { bf16x8 v; ushort u[8]; } H, L;
      #pragma unroll
      for (int j = 0; j < 8; ++j) {
        ushort hb = f2bf(vals[j]);
        H.u[j] = hb;
        L.u[j] = f2bf(vals[j] - bf2f(hb));
      }
      qh[kst] = H.v; ql[kst] = L.v;
    }
  }
  f32x4 accO[4] = {};                           // row q=lk*4+r, col d=nf*16+lr
  float m = -3.402823466e38f, lsum = 0.0f;
  int sr = tid >> 2, sd0 = (tid & 3) * 16;      // K/V staging coords
  int pd = tid & 63, pkv0 = (tid >> 6) * 16;    // V transpose coords

  for (int kt = 0; kt <= qt; ++kt) {
    __syncthreads();
    // ---- stage K -> Kh/Kl (chunk-swizzled), V -> Vf (f32, chunk-swizzled)
    {
      const float* kg = qkv + (bT + kt * 64 + sr) * 3072 + h * 192 + 64 + sd0;
      const float* vg = kg + 64;
      #pragma unroll
      for (int half = 0; half < 2; ++half) {
        float4 f0 = *(const float4*)(kg + half * 8);
        float4 f1 = *(const float4*)(kg + half * 8 + 4);
        float vals[8] = {f0.x, f0.y, f0.z, f0.w, f1.x, f1.y, f1.z, f1.w};
        union { bf16x8 v; ushort u[8]; } H, L;
        #pragma unroll
        for (int j = 0; j < 8; ++j) {
          ushort hb = f2bf(vals[j]);
          H.u[j] = hb; L.u[j] = f2bf(vals[j] - bf2f(hb));
        }
        int cs = ((sd0 >> 3) + half) ^ (sr & 7);
        *(bf16x8*)&Kh[sr * 64 + cs * 8] = H.v;
        *(bf16x8*)&Kl[sr * 64 + cs * 8] = L.v;
      }
      #pragma unroll
      for (int i = 0; i < 4; ++i) {
        float4 f = *(const float4*)(vg + i * 4);
        int c4 = (sd0 >> 2) + i;
        *(float4*)&Vf[sr * 64 + ((c4 ^ (sr & 15)) << 2)] = f;
      }
    }
    __syncthreads();
    // ---- V transpose: Vf -> Vth/Vtl (rows = d, cols = kv, chunk-swizzled)
    {
      float vv[16];
      #pragma unroll
      for (int i = 0; i < 16; ++i) {
        int kv = pkv0 + i;
        vv[i] = Vf[kv * 64 + (((pd >> 2) ^ (kv & 15)) << 2) + (pd & 3)];
      }
      #pragma unroll
      for (int half = 0; half < 2; ++half) {
        union { bf16x8 v; ushort u[8]; } H, L;
        #pragma unroll
        for (int j = 0; j < 8; ++j) {
          float x = vv[half * 8 + j];
          ushort hb = f2bf(x);
          H.u[j] = hb; L.u[j] = f2bf(x - bf2f(hb));
        }
        int cs = ((pkv0 >> 3) + half) ^ (pd & 7);
        *(bf16x8*)&Vth[pd * 64 + cs * 8] = H.v;
        *(bf16x8*)&Vtl[pd * 64 + cs * 8] = L.v;
      }
    }
    // ---- S^T = K @ Q^T  (3-term split), before Vt barrier (K is ready)
    f32x4 accS[4] = {};
    #pragma unroll
    for (int kst = 0; kst < 2; ++kst) {
      #pragma unroll
      for (int mf = 0; mf < 4; ++mf) {
        int row = mf * 16 + lr;
        int cs = (kst * 4 + lk) ^ (lr & 7);
        bf16x8 khf = *(const bf16x8*)&Kh[row * 64 + cs * 8];
        bf16x8 klf = *(const bf16x8*)&Kl[row * 64 + cs * 8];
        accS[mf] = __builtin_amdgcn_mfma_f32_16x16x32_bf16(khf, qh[kst], accS[mf], 0, 0, 0);
        accS[mf] = __builtin_amdgcn_mfma_f32_16x16x32_bf16(khf, ql[kst], accS[mf], 0, 0, 0);
        accS[mf] = __builtin_amdgcn_mfma_f32_16x16x32_bf16(klf, qh[kst], accS[mf], 0, 0, 0);
      }
    }
    __syncthreads();                            // Vth/Vtl ready
    // ---- scale + causal mask + online softmax (2 shfl_xor reduces)
    float pmax = -3.402823466e38f;
    #pragma unroll
    for (int mf = 0; mf < 4; ++mf)
      #pragma unroll
      for (int r = 0; r < 4; ++r) {
        int kvg = kt * 64 + mf * 16 + lk * 4 + r;
        float sv = (kvg <= qg) ? accS[mf][r] * 0.125f : -3.402823466e38f;
        accS[mf][r] = sv;
        pmax = fmaxf(pmax, sv);
      }
    pmax = fmaxf(pmax, __shfl_xor(pmax, 16));
    pmax = fmaxf(pmax, __shfl_xor(pmax, 32));
    float mnew = fmaxf(m, pmax);
    float fsc = expf(m - mnew);
    float psum = 0.0f;
    #pragma unroll
    for (int mf = 0; mf < 4; ++mf)
      #pragma unroll
      for (int r = 0; r < 4; ++r) {
        float p = expf(accS[mf][r] - mnew);
        accS[mf][r] = p;
        psum += p;
      }
    psum += __shfl_xor(psum, 16);
    psum += __shfl_xor(psum, 32);
    lsum = lsum * fsc + psum;
    m = mnew;
    // rescale accO: row q=lk*4+r, factor lives in lanes with lr' = lk*4+r
    #pragma unroll
    for (int r = 0; r < 4; ++r) {
      int srcF = (lane & 48) | (((lane >> 4) & 3) << 2) | r;
      float fr = __shfl(fsc, srcF);
      #pragma unroll
      for (int nf = 0; nf < 4; ++nf) accO[nf][r] *= fr;
    }
    // ---- PV: assemble P A-frags via shfl, 3-term split MFMA
    #pragma unroll
    for (int kst = 0; kst < 2; ++kst) {
      float pj[8];
      #pragma unroll
      for (int j = 0; j < 8; ++j) {
        int src = ((((lane & 16) >> 3) + (j >> 2)) << 4) | lr;
        float v0 = __shfl(accS[kst * 2][j & 3], src);
        float v1 = __shfl(accS[kst * 2 + 1][j & 3], src);
        pj[j] = (lane & 32) ? v1 : v0;
      }
      union { bf16x8 v; ushort u[8]; } PH, PL;
      #pragma unroll
      for (int j = 0; j < 8; ++j) {
        ushort hb = f2bf(pj[j]);
        PH.u[j] = hb; PL.u[j] = f2bf(pj[j] - bf2f(hb));
      }
      #pragma unroll
      for (int nf = 0; nf < 4; ++nf) {
        int row = nf * 16 + lr;
        int cs = (kst * 4 + lk) ^ (lr & 7);
        bf16x8 vhf = *(const bf16x8*)&Vth[row * 64 + cs * 8];
        bf16x8 vlf = *(const bf16x8*)&Vtl[row * 64 + cs * 8];
        accO[nf] = __builtin_amdgcn_mfma_f32_16x16x32_bf16(PH.v, vhf, accO[nf], 0, 0, 0);
        accO[nf] = __builtin_amdgcn_mfma_f32_16x16x32_bf16(PH.v, vlf, accO[nf], 0, 0, 0);
        accO[nf] = __builtin_amdgcn_mfma_f32_16x16x32_bf16(PL.v, vhf, accO[nf], 0, 0, 0);
      }
    }
  }
  // ---- epilogue: normalize and store
  #pragma unroll
  for (int r = 0; r < 4; ++r) {
    int srcF = (lane & 48) | (((lane >> 4) & 3) << 2) | r;
    float linv = __shfl(1.0f / lsum, srcF);
    int row = q0 + w * 16 + ((lane >> 4) & 3) * 4 + r;
    #pragma unroll
    for (int nf = 0; nf < 4; ++nf)
      o[(bT + row) * 1024 + h * 64 + nf * 16 + lr] = accO[nf][r] * linv;
  }
}

// ---------------------------------------------------------------- transpose + bf16 convert (+lo split)
template<bool LO>
__global__ void tconv_kernel(const float* __restrict__ in, ushort* __restrict__ oh,
                             ushort* __restrict__ ol, int K, int N) {
  __shared__ float t[32][33];
  int z = blockIdx.z;
  const float* ip = in + (size_t)z * K * N;
  ushort* ohp = oh + (size_t)z * K * N;
  ushort* olp = LO ? (ol + (size_t)z * K * N) : nullptr;
  int n0 = blockIdx.x * 32, k0 = blockIdx.y * 32;
  int tx = threadIdx.x, ty = threadIdx.y;   // (32,8)
  #pragma unroll
  for (int i = 0; i < 4; ++i)
    t[ty + 8 * i][tx] = ip[(size_t)(k0 + ty + 8 * i) * N + n0 + tx];
  __syncthreads();
  #pragma unroll
  for (int i = 0; i < 4; ++i) {
    float v = t[tx][ty + 8 * i];
    size_t off = (size_t)(n0 + ty + 8 * i) * K + k0 + tx;
    ushort hb = f2bf(v);
    ohp[off] = hb;
    if (LO) olp[off] = f2bf(v - bf2f(hb));
  }
}

// ---------------------------------------------------------------- rowwise hi/lo bf16 split
__global__ __launch_bounds__(256)
void split_kernel(const float* __restrict__ in, ushort* __restrict__ oh,
                  ushort* __restrict__ ol) {
  size_t i = ((size_t)blockIdx.x * 256 + threadIdx.x) * 4;
  float4 v = *(const float4*)(in + i);
  ushort h0 = f2bf(v.x), h1 = f2bf(v.y), h2 = f2bf(v.z), h3 = f2bf(v.w);
  ushort4 hh = {h0, h1, h2, h3};
  *(ushort4*)(oh + i) = hh;
  ushort4 ll = {f2bf(v.x - bf2f(h0)), f2bf(v.y - bf2f(h1)),
                f2bf(v.z - bf2f(h2)), f2bf(v.w - bf2f(h3))};
  *(ushort4*)(ol + i) = ll;
}

// ---------------------------------------------------------------- MFMA GEMM
// C[M][N] = A[M][K] @ B^T[N][K]  (bf16 in, fp32 acc). 128x128 tile, 4 waves.
// SPLIT3: logical K' = 3K over segments (Ah,Bh),(Ah,Bl),(Al,Bh).
// EPI: 0 fp32 C; 1 fp32 C+extra; 2 bf16 gelu(C+bias); 3 bf16 C+bias.
#define LOAD_STEP(tt) do {                                                     \
    int seg = SPLIT3 ? ((tt) / kPer) : 0;                                      \
    int kk = (SPLIT3 ? ((tt) % kPer) : (tt)) << 6;                             \
    const ushort* Ause = (SPLIT3 && seg == 2) ? AlB : AhB;                     \
    const ushort* Buse = (SPLIT3 && seg == 1) ? BlB : BhB;                     \
    _Pragma("unroll")                                                          \
    for (int q = 0; q < 4; ++q) {                                              \
      int rr = r0 + 32 * q;                                                    \
      int clog = cph ^ (rr & 7);                                               \
      ra[q] = *(const bf16x8*)(Ause + (size_t)garow[q] * K + kk + clog * 8);   \
      rb[q] = *(const bf16x8*)(Buse + (size_t)(bn + rr) * K + kk + clog * 8);  \
    }                                                                          \
  } while (0)

template<int EPI, bool GATHER, bool SPLIT3>
__global__ __launch_bounds__(256, 2)
void mgemm(const ushort* __restrict__ Ah, const ushort* __restrict__ Al,
           const ushort* __restrict__ Bh, const ushort* __restrict__ Bl,
           void* __restrict__ Cv, const float* __restrict__ extra,
           const int* __restrict__ gatAll, int N, int K,
           long aEStride, long bEStride, long cEStride, int biasEStride) {
  __shared__ ushort As[128 * 64];
  __shared__ ushort Bs[128 * 64];
  int z = blockIdx.z;
  const ushort* AhB = Ah + (size_t)z * aEStride;
  const ushort* AlB = SPLIT3 ? (Al + (size_t)z * aEStride) : nullptr;
  const ushort* BhB = Bh + (size_t)z * bEStride;
  const ushort* BlB = SPLIT3 ? (Bl + (size_t)z * bEStride) : nullptr;
  const int* gat = GATHER ? (gatAll + z * 1024) : nullptr;
  int bm = blockIdx.y * 128, bn = blockIdx.x * 128;
  int tid = threadIdx.x;
  int r0 = tid >> 3, cph = tid & 7;
  int garow[4];
  #pragma unroll
  for (int q = 0; q < 4; ++q) {
    int rr = r0 + 32 * q;
    garow[q] = GATHER ? gat[bm + rr] : (bm + rr);
  }
  int kPer = K >> 6;
  int kSteps = (SPLIT3 ? 3 : 1) * kPer;
  int wid = tid >> 6, lane = tid & 63;
  int wm = wid >> 1, wn = wid & 1;
  int lr = lane & 15, lk = lane >> 4;
  f32x4 acc[4][4] = {};
  bf16x8 ra[4], rb[4];
  LOAD_STEP(0);
  for (int t = 0; t < kSteps; ++t) {
    __syncthreads();
    #pragma unroll
    for (int q = 0; q < 4; ++q) {
      int rr = r0 + 32 * q;
      *(bf16x8*)&As[rr * 64 + cph * 8] = ra[q];
      *(bf16x8*)&Bs[rr * 64 + cph * 8] = rb[q];
    }
    __syncthreads();
    if (t + 1 < kSteps) LOAD_STEP(t + 1);
    #pragma unroll
    for (int kh = 0; kh < 2; ++kh) {
      bf16x8 af[4], bfr[4];
      #pragma unroll
      for (int mf = 0; mf < 4; ++mf) {
        int row = wm * 64 + mf * 16 + lr;
        int ch = (kh * 4 + lk) ^ (row & 7);
        af[mf] = *(const bf16x8*)&As[row * 64 + ch * 8];
      }
      #pragma unroll
      for (int nf = 0; nf < 4; ++nf) {
        int row = wn * 64 + nf * 16 + lr;
        int ch = (kh * 4 + lk) ^ (row & 7);
        bfr[nf] = *(const bf16x8*)&Bs[row * 64 + ch * 8];
      }
      #pragma unroll
      for (int mf = 0; mf < 4; ++mf)
        #pragma unroll
        for (int nf = 0; nf < 4; ++nf)
          acc[mf][nf] = __builtin_amdgcn_mfma_f32_16x16x32_bf16(af[mf], bfr[nf], acc[mf][nf], 0, 0, 0);
    }
  }
  int crow = bm + wm * 64, ccol = bn + wn * 64;
  if constexpr (EPI <= 1) {
    float* C = (float*)Cv;
    #pragma unroll
    for (int mf = 0; mf < 4; ++mf)
      #pragma unroll
      for (int nf = 0; nf < 4; ++nf)
        #pragma unroll
        for (int r = 0; r < 4; ++r) {
          int row = crow + mf * 16 + lk * 4 + r;
          int col = ccol + nf * 16 + lr;
          float v = acc[mf][nf][r];
          if constexpr (EPI == 1) v += extra[(size_t)row * N + col];
          C[(size_t)row * N + col] = v;
        }
  } else {
    const float* bias = extra + (size_t)z * biasEStride;
    ushort* C = (ushort*)Cv + (size_t)z * cEStride;
    #pragma unroll
    for (int mf = 0; mf < 4; ++mf)
      #pragma unroll
      for (int nf = 0; nf < 4; ++nf)
        #pragma unroll
        for (int r = 0; r < 4; ++r) {
          int row = crow + mf * 16 + lk * 4 + r;
          int col = ccol + nf * 16 + lr;
          float v = acc[mf][nf][r] + bias[col];
          if constexpr (EPI == 2)
            v = 0.5f * v * (1.0f + erff(v * 0.70710678118654752f));
          C[(size_t)row * N + col] = f2bf(v);
        }
  }
}

// ---------------------------------------------------------------- gate: softmax + stable top-2
__global__ __launch_bounds__(256)
void gate_kernel(const float* __restrict__ ffin, const float* __restrict__ Wg,
                 int* __restrict__ te, float* __restrict__ tv, int* __restrict__ inv) {
  int token = blockIdx.x, tid = threadIdx.x;
  float acc[8] = {};
  const float* xr = ffin + (size_t)token * 1024;
  for (int i = tid; i < 1024; i += 256) {
    float xv = xr[i];
    const float4* wr = (const float4*)&Wg[i * 8];
    float4 w0 = wr[0], w1 = wr[1];
    acc[0] += xv * w0.x; acc[1] += xv * w0.y; acc[2] += xv * w0.z; acc[3] += xv * w0.w;
    acc[4] += xv * w1.x; acc[5] += xv * w1.y; acc[6] += xv * w1.z; acc[7] += xv * w1.w;
  }
  #pragma unroll
  for (int off = 1; off < 64; off <<= 1)
    #pragma unroll
    for (int q = 0; q < 8; ++q) acc[q] += __shfl_xor(acc[q], off);
  __shared__ float red[4][8];
  if ((tid & 63) == 0)
    #pragma unroll
    for (int q = 0; q < 8; ++q) red[tid >> 6][q] = acc[q];
  __syncthreads();
  if (tid == 0) {
    float g[8];
    #pragma unroll
    for (int q = 0; q < 8; ++q) g[q] = red[0][q] + red[1][q] + red[2][q] + red[3][q];
    float mx = g[0];
    #pragma unroll
    for (int q = 1; q < 8; ++q) mx = fmaxf(mx, g[q]);
    float sum = 0.0f;
    #pragma unroll
    for (int q = 0; q < 8; ++q) { g[q] = expf(g[q] - mx); sum += g[q]; }
    float inv_s = 1.0f / sum;
    #pragma unroll
    for (int q = 0; q < 8; ++q) g[q] *= inv_s;
    int e1 = 0; float v1 = g[0];
    for (int q = 1; q < 8; ++q) if (g[q] > v1) { v1 = g[q]; e1 = q; }
    int e2 = -1; float v2 = -1.0f;
    for (int q = 0; q < 8; ++q) { if (q == e1) continue; if (g[q] > v2) { v2 = g[q]; e2 = q; } }
    te[token * 2] = e1; te[token * 2 + 1] = e2;
    tv[token * 2] = v1; tv[token * 2 + 1] = v2;
    inv[token * 2] = -1; inv[token * 2 + 1] = -1;
  }
}

// ---------------------------------------------------------------- per-expert capacity select
__global__ __launch_bounds__(1024)
void route_sort_kernel(const int* __restrict__ te, const float* __restrict__ tv,
                       int* __restrict__ etok, float* __restrict__ ew,
                       int* __restrict__ inv) {
  __shared__ unsigned long long sk[8192];
  int e = blockIdx.x, tid = threadIdx.x;
  for (int s = tid; s < 8192; s += 1024) {
    unsigned long long key = 0ull;
    if (te[s] == e) {
      unsigned vb = __float_as_uint(tv[s]);
      key = ((unsigned long long)vb << 32) | (unsigned)(0xFFFFFFFFu - (unsigned)s);
    }
    sk[s] = key;
  }
  __syncthreads();
  for (int k = 2; k <= 8192; k <<= 1)
    for (int j = k >> 1; j > 0; j >>= 1) {
      for (int t = tid; t < 4096; t += 1024) {
        int i = ((t & ~(j - 1)) << 1) | (t & (j - 1));
        int p = i | j;
        unsigned long long a = sk[i], bq = sk[p];
        bool desc = ((i & k) == 0);
        bool sw = desc ? (a < bq) : (a > bq);
        if (sw) { sk[i] = bq; sk[p] = a; }
      }
      __syncthreads();
    }
  if (tid < 1024) {
    unsigned long long key = sk[tid];
    bool valid = (key != 0ull);
    unsigned slot = 0xFFFFFFFFu - (unsigned)(key & 0xFFFFFFFFull);
    etok[e * 1024 + tid] = valid ? (int)(slot >> 1) : 0;
    ew[e * 1024 + tid] = valid ? __uint_as_float((unsigned)(key >> 32)) : 0.0f;
    if (valid) inv[slot] = e * 1024 + tid;
  }
}

// ---------------------------------------------------------------- final combine (deterministic)
__global__ __launch_bounds__(256)
void combine_kernel(const float* __restrict__ xres, const ushort* __restrict__ eo,
                    const int* __restrict__ inv, const float* __restrict__ ew,
                    float* __restrict__ outx, float* __restrict__ aux) {
  int token = blockIdx.x;
  int d = threadIdx.x * 4;
  float4 acc = *(const float4*)&xres[(size_t)token * 1024 + d];
  #pragma unroll
  for (int j = 0; j < 2; ++j) {
    int p = inv[token * 2 + j];
    if (p >= 0) {
      float w = ew[p];
      const ushort* ep = eo + (size_t)p * 1024 + d;
      acc.x += w * bf2f(ep[0]); acc.y += w * bf2f(ep[1]);
      acc.z += w * bf2f(ep[2]); acc.w += w * bf2f(ep[3]);
    }
  }
  *(float4*)&outx[(size_t)token * 1024 + d] = acc;
  if (token == 0 && threadIdx.x == 0) aux[0] = 0.0f;
}

// ================================================================ launch
extern "C" void kernel_launch(void* const* d_in, const int* in_sizes, int n_in,
                              void* d_out, int out_size, void* d_ws, size_t ws_size,
                              hipStream_t stream) {
  const float* x     = (const float*)d_in[0];
  const float* ln1g  = (const float*)d_in[1];
  const float* ln1b  = (const float*)d_in[2];
  const float* ln2g  = (const float*)d_in[3];
  const float* ln2b  = (const float*)d_in[4];
  const float* Wqkv  = (const float*)d_in[5];
  const float* Wproj = (const float*)d_in[6];
  const float* Wg    = (const float*)d_in[7];
  const float* W1    = (const float*)d_in[8];
  const float* b1    = (const float*)d_in[9];
  const float* W2    = (const float*)d_in[10];
  const float* b2    = (const float*)d_in[11];

  float* out_x   = (float*)d_out;
  float* out_aux = out_x + 4194304;
  float* out_k   = out_aux + 1;
  float* out_v   = out_k + 4194304;

  float* ws   = (float*)d_ws;
  float* A    = ws;                          // x_norm -> x_res
  float* qkvb = ws + 4194304;                // fp32 qkv (aliased by h later)
  float* o    = ws + 16777216;               // attn out -> ff_in
  float* st   = ws + 20971520;
  float* ct   = ws + 21037056;
  int*   te   = (int*)(ws + 21102592);
  float* tv   = ws + 21110784;
  int*   etok = (int*)(ws + 21118976);
  float* ew   = ws + 21127168;
  int*   inv  = (int*)(ws + 21135360);
  ushort* bfAh = (ushort*)(ws + 21143552);   // [4096][1024] bf16
  ushort* bfAl = (ushort*)(ws + 23240704);
  ushort* BqH  = (ushort*)(ws + 25337856);   // WqkvT hi [3072][1024]
  ushort* BqL  = (ushort*)(ws + 26910720);
  ushort* BpH  = (ushort*)(ws + 28483584);   // WprojT hi [1024][1024]
  ushort* BpL  = (ushort*)(ws + 29007872);
  ushort* W1t  = (ushort*)(ws + 29532160);   // [8][4096][1024]
  ushort* W2t  = (ushort*)(ws + 46309376);   // [8][1024][4096]
  ushort* eo   = (ushort*)(ws + 63086592);   // [8192][1024] bf16
  ushort* hbuf = (ushort*)(ws + 4194304);    // [8][1024][4096] bf16, aliases qkvb+o

  // weight prep (independent of activations)
  tconv_kernel<true ><<<dim3(96, 32, 1),  dim3(32, 8), 0, stream>>>(Wqkv,  BqH, BqL, 1024, 3072);
  tconv_kernel<true ><<<dim3(32, 32, 1),  dim3(32, 8), 0, stream>>>(Wproj, BpH, BpL, 1024, 1024);
  tconv_kernel<false><<<dim3(128, 32, 8), dim3(32, 8), 0, stream>>>(W1, W1t, nullptr, 1024, 4096);
  tconv_kernel<false><<<dim3(32, 128, 8), dim3(32, 8), 0, stream>>>(W2, W2t, nullptr, 4096, 1024);
  sincos_kernel<<<TT, 32, 0, stream>>>(st, ct);

  // LN1 + split
  ln_kernel<<<NTOK, 256, 0, stream>>>(x, ln1g, ln1b, A);
  split_kernel<<<4096, 256, 0, stream>>>(A, bfAh, bfAl);
  // QKV (split-bf16, K' = 3*1024)
  mgemm<0, false, true><<<dim3(24, 32, 1), 256, 0, stream>>>(
      bfAh, bfAl, BqH, BqL, qkvb, nullptr, nullptr, 3072, 1024, 0, 0, 0, 0);
  rope_kernel<<<NTOK, 256, 0, stream>>>(qkvb, st, ct, out_k, out_v);
  flash3_kernel<<<dim3(32, 16, 2), 256, 0, stream>>>(qkvb, o);
  // proj + residual (split-bf16)
  split_kernel<<<4096, 256, 0, stream>>>(o, bfAh, bfAl);
  mgemm<1, false, true><<<dim3(8, 32, 1), 256, 0, stream>>>(
      bfAh, bfAl, BpH, BpL, A, x, nullptr, 1024, 1024, 0, 0, 0, 0);
  // LN2 -> ff_in (in o buffer), gate, route
  ln_kernel<<<NTOK, 256, 0, stream>>>(A, ln2g, ln2b, o);
  gate_kernel<<<NTOK, 256, 0, stream>>>(o, Wg, te, tv, inv);
  split_kernel<<<4096, 256, 0, stream>>>(o, bfAh, bfAl);   // ffin bf16 (hi used)
  route_sort_kernel<<<8, 1024, 0, stream>>>(te, tv, etok, ew, inv);
  // experts: up (gather + gelu -> bf16 h), down (-> bf16 eo)
  mgemm<2, true, false><<<dim3(32, 8, 8), 256, 0, stream>>>(
      bfAh, nullptr, W1t, nullptr, hbuf, b1, etok, 4096, 1024,
      0, 4096L * 1024, 1024L * 4096, 4096);
  mgemm<3, false, false><<<dim3(8, 8, 8), 256, 0, stream>>>(
      hbuf, nullptr, W2t, nullptr, eo, b2, nullptr, 1024, 4096,
      1024L * 4096, 1024L * 4096, 1024L * 1024, 1024);
  combine_kernel<<<NTOK, 256, 0, stream>>>(A, eo, inv, ew, out_x, out_aux);
}